// Round 2
// baseline (845.149 us; speedup 1.0000x reference)
//
#include <hip/hip_runtime.h>

// SubdivideMeshes: verts (N,V,3) f32, faces (F,3) i32, edges (E,2) i32,
// face_to_edge (F,3) i32.
// Out (flat f32): new_verts (N, V+E, 3) then new_faces (4F, 3) as floats
// (indices < 2^24, exact in f32).
//
// R2 design: element-per-thread mapping (one thread per OUTPUT FLOAT) so
// every store instruction is lane-dense. blockIdx.y carries batch (n) or
// face-region (r) so there is no per-thread div and no divergence.

#define GRID_S 1024
#define V_CONST (GRID_S * GRID_S)  // 1048576
#define V3_CONST (V_CONST * 3)

// Kernel 1: copy verts into the head of each batch's new_verts block.
// Dense dword load + dense dword store. blockIdx.y = batch.
__global__ __launch_bounds__(256) void copy_verts_k(
    const float* __restrict__ verts,
    float* __restrict__ out,
    int rowStride3) {  // (V+E)*3
    int r = blockIdx.x * blockDim.x + threadIdx.x;   // [0, V*3)
    if (r >= V3_CONST) return;
    int n = blockIdx.y;
    out[(long)n * rowStride3 + r] = verts[(long)n * V3_CONST + r];
}

// Kernel 2: edge midpoints, one thread per output float.
// rem in [0, E*3): e = rem/3, c = rem%3. Lanes 3e..3e+2 read contiguous
// 12B chunks of verts for each endpoint -> near-dense gather (edges are
// sorted by v0). Stores fully dense.
__global__ __launch_bounds__(256) void midpoints_k(
    const float* __restrict__ verts,
    const int* __restrict__ edges,
    float* __restrict__ out,
    int E3,            // E*3
    int rowStride3) {  // (V+E)*3
    int rem = blockIdx.x * blockDim.x + threadIdx.x;
    if (rem >= E3) return;
    int n = blockIdx.y;
    int e = rem / 3;              // magic-mul div by 3
    int c = rem - 3 * e;
    int v0 = edges[2 * e];
    int v1 = edges[2 * e + 1];
    const float* b = verts + (long)n * V3_CONST;
    float val = 0.5f * (b[3 * v0 + c] + b[3 * v1 + c]);
    out[(long)n * rowStride3 + V3_CONST + rem] = val;
}

// Kernel 3: new faces, one thread per output float. blockIdx.y = region r.
//   r=0: [v0, e2+V, e1+V]; r=1: [v1, e0+V, e2+V]; r=2: [v2, e1+V, e0+V]
//   r=3: [e0+V, e1+V, e2+V]
// k=0 (r<3) -> faces[3f+r]; k=1 -> fte[3f+(r+2)%3]; k=2 -> fte[3f+(r+1)%3]
__global__ __launch_bounds__(256) void faces_k(
    const int* __restrict__ faces,
    const int* __restrict__ fte,
    float* __restrict__ out,
    int threeF,        // 3*F
    long baseOut) {    // N*(V+E)*3
    int t = blockIdx.x * blockDim.x + threadIdx.x;   // [0, 3F)
    if (t >= threeF) return;
    int r = blockIdx.y;                              // wave-uniform region
    int f = t / 3;                                   // magic-mul div by 3
    int k = t - 3 * f;
    int val;
    if (r == 3) {
        val = fte[t] + V_CONST;                      // dense load
    } else if (k == 0) {
        val = faces[3 * f + r];
    } else {
        int idx = (k == 1) ? (r + 2) % 3 : (r + 1) % 3;  // r uniform -> cheap
        val = fte[3 * f + idx] + V_CONST;
    }
    out[baseOut + (long)r * threeF + t] = (float)val;
}

extern "C" void kernel_launch(void* const* d_in, const int* in_sizes, int n_in,
                              void* d_out, int out_size, void* d_ws, size_t ws_size,
                              hipStream_t stream) {
    const float* verts = (const float*)d_in[0];
    const int* faces   = (const int*)d_in[1];
    const int* edges   = (const int*)d_in[2];
    const int* fte     = (const int*)d_in[3];
    float* out = (float*)d_out;

    const int F = in_sizes[1] / 3;
    const int E = in_sizes[2] / 2;
    const int N = in_sizes[0] / V3_CONST;

    const int rowStride3 = (V_CONST + E) * 3;    // per-batch new_verts stride
    const int E3 = E * 3;
    const int threeF = 3 * F;
    const long baseOut = (long)N * rowStride3;   // start of new_faces region

    {
        dim3 block(256);
        dim3 grid((V3_CONST + 255) / 256, N);
        copy_verts_k<<<grid, block, 0, stream>>>(verts, out, rowStride3);
    }
    {
        dim3 block(256);
        dim3 grid((E3 + 255) / 256, N);
        midpoints_k<<<grid, block, 0, stream>>>(verts, edges, out, E3, rowStride3);
    }
    {
        dim3 block(256);
        dim3 grid((threeF + 255) / 256, 4);
        faces_k<<<grid, block, 0, stream>>>(faces, fte, out, threeF, baseOut);
    }
}